// Round 17
// baseline (989.222 us; speedup 1.0000x reference)
//
#include <hip/hip_runtime.h>

// out = relu(x @ W1) @ W2
// x: [N,155] fp32, W1: [155,128] fp32, W2: [128,3] fp32, out: [N,3] fp32.
// v19: v10's free-running-wave structure at 512 threads (the config whose
//      register budget actually fits it). 8 waves/block, 128-row tiles;
//      wave w privately stages rows 16w..16w+15 (f4 range [620w,620w+620),
//      contiguous & coalesced), converts to its private xs region, MFMAs
//      against W1^T in LDS, DPP epilogue, coalesced 192B store -- ZERO
//      barriers in the tile loop, waves fully decoupled. This is the only
//      structure that staggers HBM load bursts across waves (every barriered
//      variant alternates whole-CU delivery and compute phases -> ~50% read
//      duty = the 3.3 TB/s plateau shared by v9/v14/v16/v18). v10 proved
//      the structure CORRECT (absmax passed); it died only of the 1024-thr
//      VGPR=64 cliff (pre[10] spill: WRITE 227MB, FETCH 2.0GB). 512thr at
//      (512,1) gives a ~256-reg budget (proven by v16): pre 40 + acc 32 +
//      temps ~40 fit with 2x margin. LDS = w1s 43K + xs 43K + w2s 1.5K =
//      87.5KB -> 1 block/CU, 8 waves/CU self-paced.

#define N_TOTAL 1048576
#define IN_DIM 155
#define HIDDEN 128
#define BLOCK_THREADS 512
#define TILE_ROWS 128
#define NTILES 32
#define ROWS_PER_BLOCK (TILE_ROWS * NTILES)  // 4096
#define XK 168                                // LDS k-stride (bf16): 336B rows, 2-way-free banks
#define TILE_ELEMS (TILE_ROWS * IN_DIM)       // 19840 floats
#define WAVE_F4 620                           // 16 rows * 155 floats / 4 per wave
#define F4_PER_LANE 10                        // ceil(620 / 64)

typedef __attribute__((ext_vector_type(4))) float fvec4;
typedef __attribute__((ext_vector_type(8))) short short8;   // 8 bf16 MFMA A/B frag
typedef __attribute__((ext_vector_type(4))) float floatx4;  // MFMA C/D frag

static __device__ __forceinline__ unsigned short f2bf(float f) {
  // round-to-nearest-even fp32 -> bf16 (inputs are finite normals)
  unsigned int u = __builtin_bit_cast(unsigned int, f);
  u += 0x7fffu + ((u >> 16) & 1u);
  return (unsigned short)(u >> 16);
}

// v += row_ror<N>(v): rotate within the 16-lane DPP row (VALU pipe, no DS op).
// ror 8,4,2,1 chain = full 16-lane sum in every lane. (validated v7-v18)
template <int CTRL>
static __device__ __forceinline__ float dpp_ror_add(float v) {
  const int m = __builtin_amdgcn_update_dpp(
      0, __builtin_bit_cast(int, v), CTRL, 0xf, 0xf, true);
  return v + __builtin_bit_cast(float, m);
}

__global__ __launch_bounds__(512, 1) void fused_mlp_kernel(
    const float* __restrict__ x, const float* __restrict__ W1,
    const float* __restrict__ W2, float* __restrict__ out) {
  __shared__ __align__(16) unsigned short w1s[HIDDEN * XK];    // 43008 B, W1^T bf16
  __shared__ __align__(16) unsigned short xs[TILE_ROWS * XK];  // 43008 B, x tile bf16
  __shared__ __align__(16) float w2s[HIDDEN * 3];              // 1536 B

  const int tid = threadIdx.x;
  const int ln = tid & 15;
  const int quad = (tid >> 4) & 3;  // 16-lane group within the wave
  const int wave = tid >> 6;        // 0..7
  const int l = tid & 63;

  // ---- stage W1^T as bf16 into LDS ----
  for (int idx = tid; idx < IN_DIM * HIDDEN; idx += BLOCK_THREADS) {
    const int k = idx >> 7;
    const int n = idx & 127;
    w1s[n * XK + k] = f2bf(W1[idx]);
  }
  for (int idx = tid; idx < HIDDEN * 16; idx += BLOCK_THREADS) {  // zero k-pad 155..167
    const int n = idx >> 4;
    const int k = 152 + (idx & 15);
    if (k >= IN_DIM) w1s[n * XK + k] = 0;
  }
  // zero xs k-pad cols 155..167 (never overwritten by staging)
  for (int idx = tid; idx < TILE_ROWS * 13; idx += BLOCK_THREADS) {
    const int r = idx / 13;
    const int c = IN_DIM + (idx - r * 13);
    xs[r * XK + c] = 0;
  }
  // W2 into LDS
  for (int idx = tid; idx < HIDDEN * 3; idx += BLOCK_THREADS) w2s[idx] = W2[idx];
  __syncthreads();  // the ONLY barrier: w1s/w2s read-only below; xs wave-private

  const size_t block_e0 = (size_t)blockIdx.x * ROWS_PER_BLOCK * IN_DIM;
  const size_t brow0 = (size_t)blockIdx.x * ROWS_PER_BLOCK;

  // this wave's private slice: f4 range [wbase_f4, wbase_f4+620) of each tile
  // (= rows 16*wave .. 16*wave+15; 2480 floats = exactly 16 rows, row-aligned)
  const int wbase_f4 = wave * WAVE_F4;

  // epilogue routing: dst lane l (<48) pulls from src lane 16*(l/12) + (l%12)
  const int srcaddr = ((l / 12) * 16 + (l % 12)) << 2;

  // ---- prefetch this wave's slice of tile 0 (coalesced f4, contiguous) ----
  fvec4 pre[F4_PER_LANE];
  {
    const fvec4* src = reinterpret_cast<const fvec4*>(x + block_e0);
#pragma unroll
    for (int i = 0; i < F4_PER_LANE; ++i) {
      const int fl = l + i * 64;
      if (fl < WAVE_F4) pre[i] = src[wbase_f4 + fl];
    }
  }

  for (int t = 0; t < NTILES; ++t) {
    // ---- convert this wave's 16 rows -> xs (bf16, padded rows); re-issue
    //      each pre[i]'s next-tile load right after its last read ----
    const bool more = (t + 1 < NTILES);
    const fvec4* nsrc = reinterpret_cast<const fvec4*>(
        x + block_e0 + (size_t)(t + 1) * TILE_ELEMS);
#pragma unroll
    for (int i = 0; i < F4_PER_LANE; ++i) {
      const int fl = l + i * 64;
      if (fl < WAVE_F4) {
        const fvec4 v = pre[i];
        const int e0 = (wbase_f4 + fl) * 4;  // float idx within tile region
        const int r = e0 / IN_DIM;           // in [16*wave, 16*wave+16)
        const int c = e0 - r * IN_DIM;
#pragma unroll
        for (int j = 0; j < 4; ++j) {
          const int cc = c + j;
          const int wrap = (cc >= IN_DIM);
          xs[(r + wrap) * XK + (cc - wrap * IN_DIM)] = f2bf(v[j]);
        }
        if (more) pre[i] = nsrc[wbase_f4 + fl];
      }
    }
    // no barrier: within-wave ds_write -> ds_read ordering is handled by the
    // compiler's lgkmcnt waits; other waves never touch this region.

    // ---- layer 1: 16 rows (this wave's own), B-frags from LDS ----
    floatx4 acc[8];
#pragma unroll
    for (int c8 = 0; c8 < 8; ++c8) acc[c8] = (floatx4)0.f;
    const int rbase = wave * 16;
#pragma unroll
    for (int s = 0; s < 5; ++s) {
      const int kb = s * 32 + quad * 8;
      const short8 a = *reinterpret_cast<const short8*>(&xs[(rbase + ln) * XK + kb]);
#pragma unroll
      for (int t8 = 0; t8 < 8; ++t8) {
        const short8 b = *reinterpret_cast<const short8*>(&w1s[(t8 * 16 + ln) * XK + kb]);
        acc[t8] = __builtin_amdgcn_mfma_f32_16x16x32_bf16(a, b, acc[t8], 0, 0, 0);
      }
    }

    // ---- layer 2: relu + W2, reduce across 16-lane group ----
    // acc[t8][r] = h[row0 + quad*4 + r][16*t8 + ln]
    float part[4][3];
#pragma unroll
    for (int r = 0; r < 4; ++r)
#pragma unroll
      for (int c = 0; c < 3; ++c) part[r][c] = 0.f;
#pragma unroll
    for (int t8 = 0; t8 < 8; ++t8) {
      const float wa = w2s[(t8 * 16 + ln) * 3 + 0];
      const float wb = w2s[(t8 * 16 + ln) * 3 + 1];
      const float wc = w2s[(t8 * 16 + ln) * 3 + 2];
#pragma unroll
      for (int r = 0; r < 4; ++r) {
        const float hv = fmaxf(acc[t8][r], 0.f);
        part[r][0] = fmaf(hv, wa, part[r][0]);
        part[r][1] = fmaf(hv, wb, part[r][1]);
        part[r][2] = fmaf(hv, wc, part[r][2]);
      }
    }
    // full 16-lane reduce on DPP row_ror (VALU pipe; no DS ops, no conflicts)
#pragma unroll
    for (int r = 0; r < 4; ++r)
#pragma unroll
      for (int c = 0; c < 3; ++c) {
        float v = part[r][c];
        v = dpp_ror_add<0x128>(v);  // ror 8
        v = dpp_ror_add<0x124>(v);  // ror 4
        v = dpp_ror_add<0x122>(v);  // ror 2
        v = dpp_ror_add<0x121>(v);  // ror 1
        part[r][c] = v;
      }

    // ---- single coalesced 192B store per wave ----
    // lane j (j<12) of each 16-lane group selects part[j/3][j%3] (cndmask
    // tree), then dst lane l pulls from lane 16*(l/12) + (l%12).
    float v = part[0][0];
    v = (ln == 1) ? part[0][1] : v;
    v = (ln == 2) ? part[0][2] : v;
    v = (ln == 3) ? part[1][0] : v;
    v = (ln == 4) ? part[1][1] : v;
    v = (ln == 5) ? part[1][2] : v;
    v = (ln == 6) ? part[2][0] : v;
    v = (ln == 7) ? part[2][1] : v;
    v = (ln == 8) ? part[2][2] : v;
    v = (ln == 9) ? part[3][0] : v;
    v = (ln == 10) ? part[3][1] : v;
    v = (ln == 11) ? part[3][2] : v;
    const int vo = __builtin_amdgcn_ds_bpermute(srcaddr, __builtin_bit_cast(int, v));
    const size_t row0 = brow0 + (size_t)t * TILE_ROWS + wave * 16;
    if (l < 48) out[row0 * 3 + l] = __builtin_bit_cast(float, vo);
    // no end-of-loop barrier: this wave's next overwrite of its own region is
    // ordered behind its own reads by the in-order per-wave LDS pipeline.
  }
}

extern "C" void kernel_launch(void* const* d_in, const int* in_sizes, int n_in,
                              void* d_out, int out_size, void* d_ws, size_t ws_size,
                              hipStream_t stream) {
  const float* x = (const float*)d_in[0];
  const float* W1 = (const float*)d_in[1];
  const float* W2 = (const float*)d_in[2];
  float* out = (float*)d_out;
  fused_mlp_kernel<<<dim3(N_TOTAL / ROWS_PER_BLOCK), dim3(BLOCK_THREADS), 0, stream>>>(
      x, W1, W2, out);
}

// Round 18
// 828.377 us; speedup vs baseline: 1.1942x; 1.1942x over previous
//
#include <hip/hip_runtime.h>

// out = relu(x @ W1) @ W2
// x: [N,155] fp32, W1: [155,128] fp32, W2: [128,3] fp32, out: [N,3] fp32.
// v20: v18 with EXACTLY ONE change: the 10-load next-tile prefetch burst is
//      interleaved into the MFMA s-loop (2 loads per k-step, sched_barrier(0)
//      per step so the compiler cannot re-cluster them). Hypothesis: the
//      burst fills the CU's outstanding-miss queues and parks ALL waves at
//      the load-issue instruction until delivery drains -> delivery
//      serializes ahead of compute (7.75k + 5.5k = measured 14.5k cyc/tile).
//      Interleaved, a wave parks <=2 issues then runs its 8 MFMAs; the 82KB
//      spreads across the compute phase and HBM delivers under MFMA. This
//      was v15's idea, but v15 ran at 1024 thr (hard 64-VGPR cap) where
//      stretched pre[] live ranges force spill; at (512,1) (~256-reg budget,
//      v16 uses ~220) the test is finally clean. Loads cross both
//      non-draining lds_barriers; consumed next convert via vmcnt waits.

#define N_TOTAL 1048576
#define IN_DIM 155
#define HIDDEN 128
#define BLOCK_THREADS 512
#define TILE_ROWS 128
#define NTILES 32
#define ROWS_PER_BLOCK (TILE_ROWS * NTILES)  // 4096
#define XK 168                                // LDS k-stride (bf16): 336B rows, 2-way-free banks
#define TILE_ELEMS (TILE_ROWS * IN_DIM)       // 19840 floats
#define TILE_F4 (TILE_ELEMS / 4)              // 4960 float4s
#define F4_PER_THREAD 10                      // ceil(4960 / 512)

typedef __attribute__((ext_vector_type(4))) float fvec4;
typedef __attribute__((ext_vector_type(8))) short short8;   // 8 bf16 MFMA A/B frag
typedef __attribute__((ext_vector_type(4))) float floatx4;  // MFMA C/D frag

static __device__ __forceinline__ unsigned short f2bf(float f) {
  // round-to-nearest-even fp32 -> bf16 (inputs are finite normals)
  unsigned int u = __builtin_bit_cast(unsigned int, f);
  u += 0x7fffu + ((u >> 16) & 1u);
  return (unsigned short)(u >> 16);
}

// LDS-visibility barrier WITHOUT vmcnt drain: prefetch loads stay in flight.
static __device__ __forceinline__ void lds_barrier() {
  __builtin_amdgcn_sched_barrier(0);
  asm volatile("s_waitcnt lgkmcnt(0)" ::: "memory");
  __builtin_amdgcn_s_barrier();
  __builtin_amdgcn_sched_barrier(0);
}

// v += row_ror<N>(v): rotate within the 16-lane DPP row (VALU pipe, no DS op).
template <int CTRL>
static __device__ __forceinline__ float dpp_ror_add(float v) {
  const int m = __builtin_amdgcn_update_dpp(
      0, __builtin_bit_cast(int, v), CTRL, 0xf, 0xf, true);
  return v + __builtin_bit_cast(float, m);
}

__global__ __launch_bounds__(512, 1) void fused_mlp_kernel(
    const float* __restrict__ x, const float* __restrict__ W1,
    const float* __restrict__ W2, float* __restrict__ out) {
  __shared__ __align__(16) unsigned short w1s[HIDDEN * XK];    // 43008 B
  __shared__ __align__(16) unsigned short xs[TILE_ROWS * XK];  // 43008 B
  __shared__ __align__(16) float pls[512];                     // 2048 B half-exchange

  const int tid = threadIdx.x;
  const int ln = tid & 15;
  const int quad = (tid >> 4) & 3;  // 16-lane group within the wave
  const int wave = tid >> 6;        // 0..7
  const int l = tid & 63;
  const int half = wave >> 2;  // channel half: 0 -> t8 0-3, 1 -> t8 4-7
  const int pos = wave & 3;    // row position: rows [32*pos, 32*pos+32)

  // ---- stage W1^T as bf16 into LDS (read back into registers once) ----
  for (int idx = tid; idx < IN_DIM * HIDDEN; idx += BLOCK_THREADS) {
    const int k = idx >> 7;
    const int n = idx & 127;
    w1s[n * XK + k] = f2bf(W1[idx]);
  }
  for (int idx = tid; idx < HIDDEN * 16; idx += BLOCK_THREADS) {  // zero k-pad 155..167
    const int n = idx >> 4;
    const int k = 152 + (idx & 15);
    if (k >= IN_DIM) w1s[n * XK + k] = 0;
  }
  // zero xs k-pad cols 155..167 (never overwritten by staging)
  for (int idx = tid; idx < TILE_ROWS * 13; idx += BLOCK_THREADS) {
    const int r = idx / 13;
    const int c = IN_DIM + (idx - r * 13);
    xs[r * XK + c] = 0;
  }
  // ---- W2 slice into registers (global, L2-hot, once) ----
  float w2r[4][3];
#pragma unroll
  for (int u = 0; u < 4; ++u)
#pragma unroll
    for (int c = 0; c < 3; ++c) w2r[u][c] = W2[((half * 4 + u) * 16 + ln) * 3 + c];
  __syncthreads();

  // ---- hoist this wave's B-fragments into registers (once per kernel) ----
  short8 bfr[4][5];
#pragma unroll
  for (int u = 0; u < 4; ++u)
#pragma unroll
    for (int s = 0; s < 5; ++s)
      bfr[u][s] = *reinterpret_cast<const short8*>(
          &w1s[((half * 4 + u) * 16 + ln) * XK + s * 32 + quad * 8]);

  const size_t block_e0 = (size_t)blockIdx.x * ROWS_PER_BLOCK * IN_DIM;
  const size_t brow0 = (size_t)blockIdx.x * ROWS_PER_BLOCK;

  // epilogue routing: dst lane l (<48) pulls from src lane 16*(l/12) + (l%12)
  const int srcaddr = ((l / 12) * 16 + (l % 12)) << 2;

  // ---- prefetch tile 0 into preA (one-time prologue burst) ----
  fvec4 preA[F4_PER_THREAD], preB[F4_PER_THREAD];
  {
    const fvec4* src = reinterpret_cast<const fvec4*>(x + block_e0);
#pragma unroll
    for (int i = 0; i < F4_PER_THREAD; ++i) {
      const int f = tid + i * BLOCK_THREADS;
      if (f < TILE_F4) preA[i] = src[f];
    }
  }

  // One pipeline step: convert CUR->xs, B1(non-drain), compute with NXT loads
  // interleaved 2-per-k-step (sched_barrier(0) per step prevents
  // re-clustering), epilogue + half-exchange, B2(non-drain). NXT loads stay
  // in flight across both barriers; consumed next step via vmcnt waits.
#define PIPE_STEP(T, CUR, NXT)                                                 \
  do {                                                                         \
    const int tt = (T);                                                        \
    const fvec4* nsrc = reinterpret_cast<const fvec4*>(                        \
        x + block_e0 + (size_t)((tt + 1 < NTILES) ? tt + 1 : tt) * TILE_ELEMS);\
    _Pragma("unroll") for (int i = 0; i < F4_PER_THREAD; ++i) {                \
      const int f = tid + i * BLOCK_THREADS;                                   \
      if (f < TILE_F4) {                                                       \
        const fvec4 v4 = CUR[i];                                               \
        const int e0 = f * 4;                                                  \
        const int r = e0 / IN_DIM;                                             \
        const int c = e0 - r * IN_DIM;                                         \
        _Pragma("unroll") for (int j = 0; j < 4; ++j) {                        \
          const int cc = c + j;                                                \
          const int wrap = (cc >= IN_DIM);                                     \
          xs[(r + wrap) * XK + (cc - wrap * IN_DIM)] = f2bf(v4[j]);            \
        }                                                                      \
      }                                                                        \
    }                                                                          \
    lds_barrier(); /* B1: xs visible; no vmcnt drain */                        \
    floatx4 acc0[4], acc1[4];                                                  \
    _Pragma("unroll") for (int u = 0; u < 4; ++u) {                            \
      acc0[u] = (floatx4)0.f;                                                  \
      acc1[u] = (floatx4)0.f;                                                  \
    }                                                                          \
    const int rbase = pos * 32;                                                \
    _Pragma("unroll") for (int s = 0; s < 5; ++s) {                            \
      /* issue 2 of the next tile's loads, then compute this k-step */         \
      {                                                                        \
        const int f0 = tid + (2 * s) * BLOCK_THREADS;                          \
        if (f0 < TILE_F4) NXT[2 * s] = nsrc[f0];                               \
        const int f1 = tid + (2 * s + 1) * BLOCK_THREADS;                      \
        if (f1 < TILE_F4) NXT[2 * s + 1] = nsrc[f1];                           \
      }                                                                        \
      const int kb = s * 32 + quad * 8;                                        \
      const short8 a0 =                                                        \
          *reinterpret_cast<const short8*>(&xs[(rbase + ln) * XK + kb]);       \
      const short8 a1 =                                                        \
          *reinterpret_cast<const short8*>(&xs[(rbase + 16 + ln) * XK + kb]);  \
      _Pragma("unroll") for (int u = 0; u < 4; ++u) {                          \
        acc0[u] = __builtin_amdgcn_mfma_f32_16x16x32_bf16(a0, bfr[u][s],       \
                                                          acc0[u], 0, 0, 0);  \
        acc1[u] = __builtin_amdgcn_mfma_f32_16x16x32_bf16(a1, bfr[u][s],       \
                                                          acc1[u], 0, 0, 0);  \
      }                                                                        \
      __builtin_amdgcn_sched_barrier(0); /* keep loads of step s+1 here */     \
    }                                                                          \
    float vsel0, vsel1;                                                        \
    _Pragma("unroll") for (int st = 0; st < 2; ++st) {                         \
      float part[4][3];                                                        \
      _Pragma("unroll") for (int r = 0; r < 4; ++r)                            \
          _Pragma("unroll") for (int c = 0; c < 3; ++c) part[r][c] = 0.f;      \
      _Pragma("unroll") for (int u = 0; u < 4; ++u) {                          \
        _Pragma("unroll") for (int r = 0; r < 4; ++r) {                        \
          const float hv = fmaxf(st == 0 ? acc0[u][r] : acc1[u][r], 0.f);      \
          part[r][0] = fmaf(hv, w2r[u][0], part[r][0]);                        \
          part[r][1] = fmaf(hv, w2r[u][1], part[r][1]);                        \
          part[r][2] = fmaf(hv, w2r[u][2], part[r][2]);                        \
        }                                                                      \
      }                                                                        \
      _Pragma("unroll") for (int r = 0; r < 4; ++r)                            \
          _Pragma("unroll") for (int c = 0; c < 3; ++c) {                      \
        float vv = part[r][c];                                                 \
        vv = dpp_ror_add<0x128>(vv);                                           \
        vv = dpp_ror_add<0x124>(vv);                                           \
        vv = dpp_ror_add<0x122>(vv);                                           \
        vv = dpp_ror_add<0x121>(vv);                                           \
        part[r][c] = vv;                                                       \
      }                                                                        \
      float v = part[0][0];                                                    \
      v = (ln == 1) ? part[0][1] : v;                                          \
      v = (ln == 2) ? part[0][2] : v;                                          \
      v = (ln == 3) ? part[1][0] : v;                                          \
      v = (ln == 4) ? part[1][1] : v;                                          \
      v = (ln == 5) ? part[1][2] : v;                                          \
      v = (ln == 6) ? part[2][0] : v;                                          \
      v = (ln == 7) ? part[2][1] : v;                                          \
      v = (ln == 8) ? part[2][2] : v;                                          \
      v = (ln == 9) ? part[3][0] : v;                                          \
      v = (ln == 10) ? part[3][1] : v;                                         \
      v = (ln == 11) ? part[3][2] : v;                                         \
      if (st == 0) vsel0 = v; else vsel1 = v;                                  \
    }                                                                          \
    if (half == 1 && ln < 12) {                                                \
      pls[((pos * 2 + 0) * 4 + quad) * 16 + ln] = vsel0;                       \
      pls[((pos * 2 + 1) * 4 + quad) * 16 + ln] = vsel1;                       \
    }                                                                          \
    lds_barrier(); /* B2: pls visible (lgkmcnt(0)); xs free; loads in flight */\
    if (half == 0) {                                                           \
      const float o0 = vsel0 + pls[((pos * 2 + 0) * 4 + quad) * 16 + ln];      \
      const float o1 = vsel1 + pls[((pos * 2 + 1) * 4 + quad) * 16 + ln];      \
      const int vo0 =                                                          \
          __builtin_amdgcn_ds_bpermute(srcaddr, __builtin_bit_cast(int, o0));  \
      const int vo1 =                                                          \
          __builtin_amdgcn_ds_bpermute(srcaddr, __builtin_bit_cast(int, o1));  \
      const size_t row0 = brow0 + (size_t)tt * TILE_ROWS + pos * 32;           \
      if (l < 48) {                                                            \
        out[row0 * 3 + l] = __builtin_bit_cast(float, vo0);                    \
        out[(row0 + 16) * 3 + l] = __builtin_bit_cast(float, vo1);             \
      }                                                                        \
    }                                                                          \
  } while (0)

  for (int t = 0; t < NTILES; t += 2) {
    PIPE_STEP(t, preA, preB);
    PIPE_STEP(t + 1, preB, preA);
  }
#undef PIPE_STEP
}

extern "C" void kernel_launch(void* const* d_in, const int* in_sizes, int n_in,
                              void* d_out, int out_size, void* d_ws, size_t ws_size,
                              hipStream_t stream) {
  const float* x = (const float*)d_in[0];
  const float* W1 = (const float*)d_in[1];
  const float* W2 = (const float*)d_in[2];
  float* out = (float*)d_out;
  fused_mlp_kernel<<<dim3(N_TOTAL / ROWS_PER_BLOCK), dim3(BLOCK_THREADS), 0, stream>>>(
      x, W1, W2, out);
}